// Round 2
// baseline (233.311 us; speedup 1.0000x reference)
//
#include <hip/hip_runtime.h>
#include <stdint.h>

typedef __attribute__((ext_vector_type(8))) short bf16x8;
typedef __attribute__((ext_vector_type(4))) float f32x4;
typedef __attribute__((ext_vector_type(4))) unsigned short us4;

#define NPOS 4096
#define CD 128

__device__ __forceinline__ float b2f(unsigned short u) {
  union { float f; uint32_t i; } x; x.i = ((uint32_t)u) << 16; return x.f;
}
__device__ __forceinline__ unsigned short f2b(float f) {
  union { float f; uint32_t i; } x; x.f = f;
  uint32_t r = x.i + 0x7FFFu + ((x.i >> 16) & 1u);
  return (unsigned short)(r >> 16);
}

// weight-pack element offsets inside wb
#define WQ_O 0
#define WK_O 16384
#define WV_O 32768
#define W1_O 49152
#define W2_O 57344
#define W3_O 61440
#define BQ_O 69632
#define BK_O 69760
#define BV_O 69888
#define B1_O 70016
#define G1_O 70080
#define BE1_O 70144
#define B2_O 70208
#define G2_O 70272
#define BE2_O 70336
#define B3_O 70400
#define WB_ELEMS 70656

// ---------- Kernel 0: dtype probe ----------
// attention is uniform[0,1). If buffer is fp32, even u16 halves are random
// mantissa bits -> decode huge as bf16. If bf16, they are values < 1.
__global__ __launch_bounds__(64) void probe_kernel(const unsigned short* __restrict__ att_u16,
                                                   int* __restrict__ flag) {
  int lane = threadIdx.x;
  float mx = 0.f;
  for (int k = lane; k < 4096; k += 64) {
    float v = fabsf(b2f(att_u16[2 * k]));
    if (v > mx && v == v) mx = v;  // ignore NaN decodes
  }
  unsigned long long b = __ballot(mx > 100.f);
  if (lane == 0) *flag = (b != 0ull) ? 1 : 0;
}

// ---------- Kernel 1: convert feat + weights to canonical bf16 ----------
__device__ __forceinline__ void cvt_range(const void* src, unsigned short* dst, int n,
                                          bool f32, int tid, int nthreads) {
  if (f32) {
    const float* s = (const float*)src;
    for (int i = tid; i < n; i += nthreads) dst[i] = f2b(s[i]);
  } else {
    const unsigned short* s = (const unsigned short*)src;
    for (int i = tid; i < n; i += nthreads) dst[i] = s[i];
  }
}

__global__ __launch_bounds__(256) void prep_kernel(
    const int* __restrict__ flag, const void* feat,
    const void* Wq, const void* bq, const void* Wk, const void* bk,
    const void* Wv, const void* bv, const void* W1, const void* b1,
    const void* g1, const void* be1, const void* W2, const void* b2,
    const void* g2, const void* be2, const void* W3, const void* b3,
    unsigned short* __restrict__ featb, unsigned short* __restrict__ wb) {
  bool f32 = (*flag != 0);
  int tid = blockIdx.x * 256 + threadIdx.x;
  int nt = gridDim.x * 256;
  cvt_range(feat, featb, 2 * CD * NPOS, f32, tid, nt);
  cvt_range(Wq, wb + WQ_O, 16384, f32, tid, nt);
  cvt_range(Wk, wb + WK_O, 16384, f32, tid, nt);
  cvt_range(Wv, wb + WV_O, 16384, f32, tid, nt);
  cvt_range(W1, wb + W1_O, 8192, f32, tid, nt);
  cvt_range(W2, wb + W2_O, 4096, f32, tid, nt);
  cvt_range(W3, wb + W3_O, 8192, f32, tid, nt);
  cvt_range(bq, wb + BQ_O, 128, f32, tid, nt);
  cvt_range(bk, wb + BK_O, 128, f32, tid, nt);
  cvt_range(bv, wb + BV_O, 128, f32, tid, nt);
  cvt_range(b1, wb + B1_O, 64, f32, tid, nt);
  cvt_range(g1, wb + G1_O, 64, f32, tid, nt);
  cvt_range(be1, wb + BE1_O, 64, f32, tid, nt);
  cvt_range(b2, wb + B2_O, 64, f32, tid, nt);
  cvt_range(g2, wb + G2_O, 64, f32, tid, nt);
  cvt_range(be2, wb + BE2_O, 64, f32, tid, nt);
  cvt_range(b3, wb + B3_O, 128, f32, tid, nt);
}

// ---------- Kernel 2: QKV projections ----------
// grid (32 ntiles, 3 proj, 2 batch), block 256
// Writes Q^T, K^T as [b][n][c]; V as [b][c][n].
__global__ __launch_bounds__(256) void qkv_kernel(
    const unsigned short* __restrict__ featb, const unsigned short* __restrict__ wb,
    unsigned short* __restrict__ QT, unsigned short* __restrict__ KT,
    unsigned short* __restrict__ Vm) {
  __shared__ __attribute__((aligned(16))) unsigned short X[128][136];  // feat tile [c][n]
  int tid = threadIdx.x;
  int w = tid >> 6, lane = tid & 63;
  int hi = lane >> 4, lo = lane & 15;
  int n0 = blockIdx.x * 128;
  int proj = blockIdx.y;
  int bat = blockIdx.z;
  const unsigned short* W = wb + (proj == 0 ? WQ_O : (proj == 1 ? WK_O : WV_O));
  const unsigned short* bias = wb + (proj == 0 ? BQ_O : (proj == 1 ? BK_O : BV_O));

  #pragma unroll
  for (int it = 0; it < 8; ++it) {
    int row = it * 16 + (tid >> 4);
    int col = (tid & 15) * 8;
    *(bf16x8*)&X[row][col] =
        *(const bf16x8*)(featb + ((size_t)(bat * CD + row)) * NPOS + n0 + col);
  }
  __syncthreads();

  int wr = w >> 1, wc = w & 1;  // 2x2 wave grid over 128x128 out tile
  f32x4 acc[4][4];
  #pragma unroll
  for (int m = 0; m < 4; ++m)
    #pragma unroll
    for (int n = 0; n < 4; ++n) acc[m][n] = (f32x4){0.f, 0.f, 0.f, 0.f};

  #pragma unroll
  for (int ks = 0; ks < 4; ++ks) {
    int c0 = ks * 32 + 8 * hi;
    bf16x8 a[4], bb[4];
    #pragma unroll
    for (int m = 0; m < 4; ++m) {
      int o = wr * 64 + m * 16 + lo;
      a[m] = *(const bf16x8*)(W + o * CD + c0);
    }
    #pragma unroll
    for (int n = 0; n < 4; ++n) {
      int nn = wc * 64 + n * 16 + lo;
      bf16x8 t;
      #pragma unroll
      for (int e = 0; e < 8; ++e) t[e] = (short)X[c0 + e][nn];
      bb[n] = t;
    }
    #pragma unroll
    for (int m = 0; m < 4; ++m)
      #pragma unroll
      for (int n = 0; n < 4; ++n)
        acc[m][n] = __builtin_amdgcn_mfma_f32_16x16x32_bf16(a[m], bb[n], acc[m][n], 0, 0, 0);
  }

  #pragma unroll
  for (int m = 0; m < 4; ++m) {
    int o0 = wr * 64 + m * 16 + hi * 4;
    float bsv[4];
    #pragma unroll
    for (int r = 0; r < 4; ++r) bsv[r] = b2f(bias[o0 + r]);
    #pragma unroll
    for (int n = 0; n < 4; ++n) {
      int nn = n0 + wc * 64 + n * 16 + lo;
      if (proj < 2) {
        unsigned short* O = proj == 0 ? QT : KT;
        us4 pk;
        #pragma unroll
        for (int r = 0; r < 4; ++r) pk[r] = f2b(acc[m][n][r] + bsv[r]);
        *(us4*)(O + ((size_t)(bat * NPOS + nn)) * CD + o0) = pk;
      } else {
        #pragma unroll
        for (int r = 0; r < 4; ++r)
          Vm[((size_t)(bat * CD + o0 + r)) * NPOS + nn] = f2b(acc[m][n][r] + bsv[r]);
      }
    }
  }
}

// ---------- Kernel 3: fused attention ----------
// grid (128 o-tiles of 32 rows, 2 batch), block 256 (4 waves, each a 64-wide i slice)
__global__ __launch_bounds__(256, 2) void attn_kernel(
    const int* __restrict__ flag,
    const unsigned short* __restrict__ QT, const unsigned short* __restrict__ KT,
    const unsigned short* __restrict__ Vm, const void* __restrict__ att,
    const void* __restrict__ Hm, unsigned short* __restrict__ MT) {
  __shared__ __attribute__((aligned(16))) unsigned short P[4][32][72];
  __shared__ float mred[4][32], lred[4][32];
  __shared__ float Olds[32][132];

  bool f32 = (*flag != 0);
  const float* attf = (const float*)att;
  const float* hmf = (const float*)Hm;
  const unsigned short* attu = (const unsigned short*)att;
  const unsigned short* hmu = (const unsigned short*)Hm;

  int tid = threadIdx.x;
  int w = tid >> 6, lane = tid & 63;
  int hi = lane >> 4, lo = lane & 15;
  int ob = blockIdx.x * 32;
  int bat = blockIdx.y;
  const float SCL = 0.088388347648318447f;  // 1/sqrt(128)

  bf16x8 aq[2][4];
  #pragma unroll
  for (int rf = 0; rf < 2; ++rf)
    #pragma unroll
    for (int ks = 0; ks < 4; ++ks)
      aq[rf][ks] = *(const bf16x8*)(QT + ((size_t)(bat * NPOS + ob + rf * 16 + lo)) * CD +
                                    ks * 32 + 8 * hi);

  f32x4 oacc[2][8];
  #pragma unroll
  for (int rf = 0; rf < 2; ++rf)
    #pragma unroll
    for (int c8 = 0; c8 < 8; ++c8) oacc[rf][c8] = (f32x4){0.f, 0.f, 0.f, 0.f};
  float mrun[2][4], lrun[2][4];
  #pragma unroll
  for (int rf = 0; rf < 2; ++rf)
    #pragma unroll
    for (int r = 0; r < 4; ++r) { mrun[rf][r] = -1e30f; lrun[rf][r] = 0.f; }

  for (int it = 0; it < 16; ++it) {
    int i0 = it * 256 + w * 64;

    // att/H loads for this wave's S tile (in MFMA D-layout coords)
    float av[2][4][4];
    unsigned mbits[2] = {0u, 0u};
    #pragma unroll
    for (int rf = 0; rf < 2; ++rf)
      #pragma unroll
      for (int cf = 0; cf < 4; ++cf)
        #pragma unroll
        for (int r = 0; r < 4; ++r) {
          size_t idx = ((size_t)(bat * NPOS + ob + rf * 16 + hi * 4 + r)) * NPOS +
                       i0 + cf * 16 + lo;
          float a, h;
          if (f32) { a = attf[idx]; h = hmf[idx]; }
          else     { a = b2f(attu[idx]); h = b2f(hmu[idx]); }
          av[rf][cf][r] = a;
          if (h < 0.5f) mbits[rf] |= 1u << (cf * 4 + r);
        }

    // S = Q^T K
    f32x4 s[2][4];
    #pragma unroll
    for (int rf = 0; rf < 2; ++rf)
      #pragma unroll
      for (int cf = 0; cf < 4; ++cf) s[rf][cf] = (f32x4){0.f, 0.f, 0.f, 0.f};
    #pragma unroll
    for (int cf = 0; cf < 4; ++cf) {
      #pragma unroll
      for (int ks = 0; ks < 4; ++ks) {
        bf16x8 bb = *(const bf16x8*)(KT + ((size_t)(bat * NPOS + i0 + cf * 16 + lo)) * CD +
                                     ks * 32 + 8 * hi);
        s[0][cf] = __builtin_amdgcn_mfma_f32_16x16x32_bf16(aq[0][ks], bb, s[0][cf], 0, 0, 0);
        s[1][cf] = __builtin_amdgcn_mfma_f32_16x16x32_bf16(aq[1][ks], bb, s[1][cf], 0, 0, 0);
      }
    }

    // logits in place: av <- att*(S*SCL) or -1e9 where masked
    #pragma unroll
    for (int rf = 0; rf < 2; ++rf)
      #pragma unroll
      for (int cf = 0; cf < 4; ++cf)
        #pragma unroll
        for (int r = 0; r < 4; ++r) {
          float x = av[rf][cf][r] * (s[rf][cf][r] * SCL);
          av[rf][cf][r] = ((mbits[rf] >> (cf * 4 + r)) & 1u) ? -1e9f : x;
        }

    // per-row tile max (across cf, then across 16 lanes of the group)
    float mtile[2][4];
    #pragma unroll
    for (int rf = 0; rf < 2; ++rf)
      #pragma unroll
      for (int r = 0; r < 4; ++r) {
        float v = fmaxf(fmaxf(av[rf][0][r], av[rf][1][r]), fmaxf(av[rf][2][r], av[rf][3][r]));
        #pragma unroll
        for (int d = 1; d < 16; d <<= 1) v = fmaxf(v, __shfl_xor(v, d, 64));
        mtile[rf][r] = v;
      }

    // online-softmax update
    float psc[2][4];
    #pragma unroll
    for (int rf = 0; rf < 2; ++rf)
      #pragma unroll
      for (int r = 0; r < 4; ++r) {
        float mo = mrun[rf][r];
        float mn = fmaxf(mo, mtile[rf][r]);
        float sc = __expf(mo - mn);
        mrun[rf][r] = mn;
        lrun[rf][r] *= sc;
        psc[rf][r] = sc;
      }
    #pragma unroll
    for (int rf = 0; rf < 2; ++rf)
      #pragma unroll
      for (int c8 = 0; c8 < 8; ++c8)
        #pragma unroll
        for (int r = 0; r < 4; ++r) oacc[rf][c8][r] *= psc[rf][r];

    // P = exp(lg - m) -> per-wave LDS (D-layout -> A-layout relayout)
    #pragma unroll
    for (int rf = 0; rf < 2; ++rf)
      #pragma unroll
      for (int cf = 0; cf < 4; ++cf)
        #pragma unroll
        for (int r = 0; r < 4; ++r) {
          float p = __expf(av[rf][cf][r] - mrun[rf][r]);
          lrun[rf][r] += p;
          P[w][rf * 16 + hi * 4 + r][cf * 16 + lo] = f2b(p);
        }

    // PV accumulate
    bf16x8 pa[2][2];
    #pragma unroll
    for (int rf = 0; rf < 2; ++rf)
      #pragma unroll
      for (int k2 = 0; k2 < 2; ++k2)
        pa[rf][k2] = *(const bf16x8*)&P[w][rf * 16 + lo][k2 * 32 + 8 * hi];
    #pragma unroll
    for (int k2 = 0; k2 < 2; ++k2)
      #pragma unroll
      for (int c8 = 0; c8 < 8; ++c8) {
        bf16x8 bb = *(const bf16x8*)(Vm + ((size_t)(bat * CD + c8 * 16 + lo)) * NPOS +
                                     i0 + k2 * 32 + 8 * hi);
        oacc[0][c8] = __builtin_amdgcn_mfma_f32_16x16x32_bf16(pa[0][k2], bb, oacc[0][c8], 0, 0, 0);
        oacc[1][c8] = __builtin_amdgcn_mfma_f32_16x16x32_bf16(pa[1][k2], bb, oacc[1][c8], 0, 0, 0);
      }
  }

  // cross-wave merge
  #pragma unroll
  for (int rf = 0; rf < 2; ++rf)
    #pragma unroll
    for (int r = 0; r < 4; ++r) {
      float v = lrun[rf][r];
      #pragma unroll
      for (int d = 1; d < 16; d <<= 1) v += __shfl_xor(v, d, 64);
      if (lo == 0) {
        mred[w][rf * 16 + hi * 4 + r] = mrun[rf][r];
        lred[w][rf * 16 + hi * 4 + r] = v;
      }
    }
  __syncthreads();

  float fsc[2][4];
  #pragma unroll
  for (int rf = 0; rf < 2; ++rf)
    #pragma unroll
    for (int r = 0; r < 4; ++r) {
      int row = rf * 16 + hi * 4 + r;
      float ms = fmaxf(fmaxf(mred[0][row], mred[1][row]), fmaxf(mred[2][row], mred[3][row]));
      fsc[rf][r] = __expf(mrun[rf][r] - ms);
    }
  #pragma unroll
  for (int rf = 0; rf < 2; ++rf)
    #pragma unroll
    for (int c8 = 0; c8 < 8; ++c8)
      #pragma unroll
      for (int r = 0; r < 4; ++r) oacc[rf][c8][r] *= fsc[rf][r];

  for (int v = 0; v < 4; ++v) {
    if (w == v) {
      #pragma unroll
      for (int rf = 0; rf < 2; ++rf)
        #pragma unroll
        for (int c8 = 0; c8 < 8; ++c8)
          #pragma unroll
          for (int r = 0; r < 4; ++r) {
            int row = rf * 16 + hi * 4 + r, col = c8 * 16 + lo;
            if (v == 0) Olds[row][col] = oacc[rf][c8][r];
            else Olds[row][col] += oacc[rf][c8][r];
          }
    }
    __syncthreads();
  }

  {
    int row = tid >> 3, c0 = (tid & 7) * 16;
    float ms = fmaxf(fmaxf(mred[0][row], mred[1][row]), fmaxf(mred[2][row], mred[3][row]));
    float L = 0.f;
    #pragma unroll
    for (int v = 0; v < 4; ++v) L += lred[v][row] * __expf(mred[v][row] - ms);
    float inv = 1.f / fmaxf(L, 1e-30f);
    bf16x8 p1, p2;
    #pragma unroll
    for (int j = 0; j < 8; ++j) p1[j] = (short)f2b(Olds[row][c0 + j] * inv);
    #pragma unroll
    for (int j = 0; j < 8; ++j) p2[j] = (short)f2b(Olds[row][c0 + 8 + j] * inv);
    unsigned short* dst = MT + ((size_t)(bat * NPOS + ob + row)) * CD + c0;
    *(bf16x8*)dst = p1;
    *(bf16x8*)(dst + 8) = p2;
  }
}

// ---------- Kernel 4: fused MLP + residual ----------
// grid (32 ntiles, 2 batch), block 256; wave w owns 32 positions through all layers
__global__ __launch_bounds__(256) void mlp_kernel(
    const int* __restrict__ flag,
    const unsigned short* __restrict__ MT, const unsigned short* __restrict__ featb,
    const unsigned short* __restrict__ wb, void* __restrict__ out) {
  __shared__ __attribute__((aligned(16))) unsigned short M1T[128][72];
  __shared__ __attribute__((aligned(16))) unsigned short M2T[128][72];
  __shared__ __attribute__((aligned(16))) unsigned short OT[128][136];
  __shared__ float A1[64], B1[64], A2[64], B2[64], BI3[128];

  bool f32 = (*flag != 0);
  int tid = threadIdx.x;
  int w = tid >> 6, lane = tid & 63;
  int hi = lane >> 4, lo = lane & 15;
  int n0 = blockIdx.x * 128;
  int bat = blockIdx.y;

  float rs = rsqrtf(1.0f + 1e-5f);
  if (tid < 64) {
    float s1 = b2f(wb[G1_O + tid]) * rs;
    A1[tid] = s1; B1[tid] = s1 * b2f(wb[B1_O + tid]) + b2f(wb[BE1_O + tid]);
    float s2 = b2f(wb[G2_O + tid]) * rs;
    A2[tid] = s2; B2[tid] = s2 * b2f(wb[B2_O + tid]) + b2f(wb[BE2_O + tid]);
  }
  if (tid < 128) BI3[tid] = b2f(wb[B3_O + tid]);
  __syncthreads();

  // layer 1: [64h x 32n] = W1[64x128] @ msg[128 x 32n]
  f32x4 acc1[4][2];
  #pragma unroll
  for (int m = 0; m < 4; ++m)
    #pragma unroll
    for (int n = 0; n < 2; ++n) acc1[m][n] = (f32x4){0.f, 0.f, 0.f, 0.f};
  #pragma unroll
  for (int ks = 0; ks < 4; ++ks) {
    bf16x8 bw[2];
    #pragma unroll
    for (int n = 0; n < 2; ++n)
      bw[n] = *(const bf16x8*)(MT + ((size_t)(bat * NPOS + n0 + w * 32 + n * 16 + lo)) * CD +
                               ks * 32 + 8 * hi);
    #pragma unroll
    for (int m = 0; m < 4; ++m) {
      bf16x8 aw = *(const bf16x8*)(wb + W1_O + (m * 16 + lo) * CD + ks * 32 + 8 * hi);
      #pragma unroll
      for (int n = 0; n < 2; ++n)
        acc1[m][n] = __builtin_amdgcn_mfma_f32_16x16x32_bf16(aw, bw[n], acc1[m][n], 0, 0, 0);
    }
  }
  #pragma unroll
  for (int m = 0; m < 4; ++m)
    #pragma unroll
    for (int n = 0; n < 2; ++n) {
      int h0 = m * 16 + hi * 4;
      int nn = w * 32 + n * 16 + lo;
      us4 pk;
      #pragma unroll
      for (int r = 0; r < 4; ++r) {
        float v = A1[h0 + r] * acc1[m][n][r] + B1[h0 + r];
        pk[r] = f2b(fmaxf(v, 0.f));
      }
      *(us4*)&M1T[nn][h0] = pk;
    }

  // layer 2: [64 x 32n] = W2[64x64] @ m1
  f32x4 acc2[4][2];
  #pragma unroll
  for (int m = 0; m < 4; ++m)
    #pragma unroll
    for (int n = 0; n < 2; ++n) acc2[m][n] = (f32x4){0.f, 0.f, 0.f, 0.f};
  #pragma unroll
  for (int ks = 0; ks < 2; ++ks) {
    bf16x8 bw[2];
    #pragma unroll
    for (int n = 0; n < 2; ++n)
      bw[n] = *(const bf16x8*)&M1T[w * 32 + n * 16 + lo][ks * 32 + 8 * hi];
    #pragma unroll
    for (int m = 0; m < 4; ++m) {
      bf16x8 aw = *(const bf16x8*)(wb + W2_O + (m * 16 + lo) * 64 + ks * 32 + 8 * hi);
      #pragma unroll
      for (int n = 0; n < 2; ++n)
        acc2[m][n] = __builtin_amdgcn_mfma_f32_16x16x32_bf16(aw, bw[n], acc2[m][n], 0, 0, 0);
    }
  }
  #pragma unroll
  for (int m = 0; m < 4; ++m)
    #pragma unroll
    for (int n = 0; n < 2; ++n) {
      int h0 = m * 16 + hi * 4;
      int nn = w * 32 + n * 16 + lo;
      us4 pk;
      #pragma unroll
      for (int r = 0; r < 4; ++r) {
        float v = A2[h0 + r] * acc2[m][n][r] + B2[h0 + r];
        pk[r] = f2b(fmaxf(v, 0.f));
      }
      *(us4*)&M2T[nn][h0] = pk;
    }

  // layer 3: [128c x 32n] = W3[128x64] @ m2
  f32x4 acc3[8][2];
  #pragma unroll
  for (int m = 0; m < 8; ++m)
    #pragma unroll
    for (int n = 0; n < 2; ++n) acc3[m][n] = (f32x4){0.f, 0.f, 0.f, 0.f};
  #pragma unroll
  for (int ks = 0; ks < 2; ++ks) {
    bf16x8 bw[2];
    #pragma unroll
    for (int n = 0; n < 2; ++n)
      bw[n] = *(const bf16x8*)&M2T[w * 32 + n * 16 + lo][ks * 32 + 8 * hi];
    #pragma unroll
    for (int m = 0; m < 8; ++m) {
      bf16x8 aw = *(const bf16x8*)(wb + W3_O + (m * 16 + lo) * 64 + ks * 32 + 8 * hi);
      #pragma unroll
      for (int n = 0; n < 2; ++n)
        acc3[m][n] = __builtin_amdgcn_mfma_f32_16x16x32_bf16(aw, bw[n], acc3[m][n], 0, 0, 0);
    }
  }
  #pragma unroll
  for (int m = 0; m < 8; ++m)
    #pragma unroll
    for (int n = 0; n < 2; ++n)
      #pragma unroll
      for (int r = 0; r < 4; ++r) {
        int c = m * 16 + hi * 4 + r;
        int nn = w * 32 + n * 16 + lo;
        OT[c][nn] = f2b(acc3[m][n][r] + BI3[c]);
      }
  __syncthreads();

  // copy out + residual (coalesced), dtype-adaptive store
  {
    int c = tid >> 1, nb = (tid & 1) * 64;
    #pragma unroll
    for (int j = 0; j < 8; ++j) {
      bf16x8 mv = *(bf16x8*)&OT[c][nb + 8 * j];
      const unsigned short* fp = featb + ((size_t)(bat * CD + c)) * NPOS + n0 + nb + 8 * j;
      bf16x8 fv = *(const bf16x8*)fp;
      float vals[8];
      #pragma unroll
      for (int e = 0; e < 8; ++e)
        vals[e] = b2f((unsigned short)mv[e]) + b2f((unsigned short)fv[e]);
      size_t oidx = ((size_t)(bat * CD + c)) * NPOS + n0 + nb + 8 * j;
      if (f32) {
        float* of = (float*)out;
        f32x4 v0 = {vals[0], vals[1], vals[2], vals[3]};
        f32x4 v1 = {vals[4], vals[5], vals[6], vals[7]};
        *(f32x4*)(of + oidx) = v0;
        *(f32x4*)(of + oidx + 4) = v1;
      } else {
        unsigned short* ou = (unsigned short*)out;
        bf16x8 ov;
        #pragma unroll
        for (int e = 0; e < 8; ++e) ov[e] = (short)f2b(vals[e]);
        *(bf16x8*)(ou + oidx) = ov;
      }
    }
  }
}

extern "C" void kernel_launch(void* const* d_in, const int* in_sizes, int n_in,
                              void* d_out, int out_size, void* d_ws, size_t ws_size,
                              hipStream_t stream) {
  const void* feat = d_in[0];
  const void* att  = d_in[1];
  const void* Wq = d_in[2];  const void* bq = d_in[3];
  const void* Wk = d_in[4];  const void* bk = d_in[5];
  const void* Wv = d_in[6];  const void* bv = d_in[7];
  const void* W1 = d_in[8];  const void* b1 = d_in[9];
  const void* g1 = d_in[10]; const void* be1 = d_in[11];
  const void* W2 = d_in[12]; const void* b2 = d_in[13];
  const void* g2 = d_in[14]; const void* be2 = d_in[15];
  const void* W3 = d_in[16]; const void* b3 = d_in[17];
  const void* Hm = d_in[18];

  int* flag = (int*)d_ws;
  unsigned short* base = (unsigned short*)((char*)d_ws + 256);
  unsigned short* featb = base;                        // 1,048,576
  unsigned short* wb = featb + (size_t)2 * CD * NPOS;  // 70,656
  unsigned short* QT = wb + WB_ELEMS;                  // [2][4096][128]
  unsigned short* KT = QT + (size_t)2 * NPOS * CD;     // [2][4096][128]
  unsigned short* Vm = KT + (size_t)2 * NPOS * CD;     // [2][128][4096]
  unsigned short* MT = Vm + (size_t)2 * NPOS * CD;     // [2][4096][128]

  hipLaunchKernelGGL(probe_kernel, dim3(1), dim3(64), 0, stream,
                     (const unsigned short*)att, flag);
  hipLaunchKernelGGL(prep_kernel, dim3(256), dim3(256), 0, stream,
                     flag, feat, Wq, bq, Wk, bk, Wv, bv, W1, b1, g1, be1,
                     W2, b2, g2, be2, W3, b3, featb, wb);
  hipLaunchKernelGGL(qkv_kernel, dim3(32, 3, 2), dim3(256), 0, stream,
                     featb, wb, QT, KT, Vm);
  hipLaunchKernelGGL(attn_kernel, dim3(128, 2), dim3(256), 0, stream,
                     flag, QT, KT, Vm, att, Hm, MT);
  hipLaunchKernelGGL(mlp_kernel, dim3(32, 2), dim3(256), 0, stream,
                     flag, MT, featb, wb, d_out);
}

// Round 3
// 167.528 us; speedup vs baseline: 1.3927x; 1.3927x over previous
//
#include <hip/hip_runtime.h>
#include <stdint.h>

typedef __attribute__((ext_vector_type(8))) short bf16x8;
typedef __attribute__((ext_vector_type(4))) float f32x4;
typedef __attribute__((ext_vector_type(4))) unsigned short us4;

#define NPOS 4096
#define CD 128

__device__ __forceinline__ float b2f(unsigned short u) {
  union { float f; uint32_t i; } x; x.i = ((uint32_t)u) << 16; return x.f;
}
__device__ __forceinline__ unsigned short f2b(float f) {
  union { float f; uint32_t i; } x; x.f = f;
  uint32_t r = x.i + 0x7FFFu + ((x.i >> 16) & 1u);
  return (unsigned short)(r >> 16);
}

// weight-pack element offsets inside wb
#define WQ_O 0
#define WK_O 16384
#define WV_O 32768
#define W1_O 49152
#define W2_O 57344
#define W3_O 61440
#define BQ_O 69632
#define BK_O 69760
#define BV_O 69888
#define B1_O 70016
#define G1_O 70080
#define BE1_O 70144
#define B2_O 70208
#define G2_O 70272
#define BE2_O 70336
#define B3_O 70400
#define WB_ELEMS 70656

// ---------- Kernel 0: dtype probe ----------
__global__ __launch_bounds__(64) void probe_kernel(const unsigned short* __restrict__ att_u16,
                                                   int* __restrict__ flag) {
  int lane = threadIdx.x;
  float mx = 0.f;
  for (int k = lane; k < 4096; k += 64) {
    float v = fabsf(b2f(att_u16[2 * k]));
    if (v > mx && v == v) mx = v;
  }
  unsigned long long b = __ballot(mx > 100.f);
  if (lane == 0) *flag = (b != 0ull) ? 1 : 0;
}

// ---------- Kernel 1: convert feat + weights to canonical bf16 ----------
__device__ __forceinline__ void cvt_range(const void* src, unsigned short* dst, int n,
                                          bool f32, int tid, int nthreads) {
  if (f32) {
    const float* s = (const float*)src;
    for (int i = tid; i < n; i += nthreads) dst[i] = f2b(s[i]);
  } else {
    const unsigned short* s = (const unsigned short*)src;
    for (int i = tid; i < n; i += nthreads) dst[i] = s[i];
  }
}

__global__ __launch_bounds__(256) void prep_kernel(
    const int* __restrict__ flag, const void* feat,
    const void* Wq, const void* bq, const void* Wk, const void* bk,
    const void* Wv, const void* bv, const void* W1, const void* b1,
    const void* g1, const void* be1, const void* W2, const void* b2,
    const void* g2, const void* be2, const void* W3, const void* b3,
    unsigned short* __restrict__ featb, unsigned short* __restrict__ wb) {
  bool f32 = (*flag != 0);
  int tid = blockIdx.x * 256 + threadIdx.x;
  int nt = gridDim.x * 256;
  cvt_range(feat, featb, 2 * CD * NPOS, f32, tid, nt);
  cvt_range(Wq, wb + WQ_O, 16384, f32, tid, nt);
  cvt_range(Wk, wb + WK_O, 16384, f32, tid, nt);
  cvt_range(Wv, wb + WV_O, 16384, f32, tid, nt);
  cvt_range(W1, wb + W1_O, 8192, f32, tid, nt);
  cvt_range(W2, wb + W2_O, 4096, f32, tid, nt);
  cvt_range(W3, wb + W3_O, 8192, f32, tid, nt);
  cvt_range(bq, wb + BQ_O, 128, f32, tid, nt);
  cvt_range(bk, wb + BK_O, 128, f32, tid, nt);
  cvt_range(bv, wb + BV_O, 128, f32, tid, nt);
  cvt_range(b1, wb + B1_O, 64, f32, tid, nt);
  cvt_range(g1, wb + G1_O, 64, f32, tid, nt);
  cvt_range(be1, wb + BE1_O, 64, f32, tid, nt);
  cvt_range(b2, wb + B2_O, 64, f32, tid, nt);
  cvt_range(g2, wb + G2_O, 64, f32, tid, nt);
  cvt_range(be2, wb + BE2_O, 64, f32, tid, nt);
  cvt_range(b3, wb + B3_O, 128, f32, tid, nt);
}

// ---------- Kernel 2: QKV projections ----------
__global__ __launch_bounds__(256) void qkv_kernel(
    const unsigned short* __restrict__ featb, const unsigned short* __restrict__ wb,
    unsigned short* __restrict__ QT, unsigned short* __restrict__ KT,
    unsigned short* __restrict__ Vm) {
  __shared__ __attribute__((aligned(16))) unsigned short X[128][136];  // feat tile [c][n]
  int tid = threadIdx.x;
  int w = tid >> 6, lane = tid & 63;
  int hi = lane >> 4, lo = lane & 15;
  int n0 = blockIdx.x * 128;
  int proj = blockIdx.y;
  int bat = blockIdx.z;
  const unsigned short* W = wb + (proj == 0 ? WQ_O : (proj == 1 ? WK_O : WV_O));
  const unsigned short* bias = wb + (proj == 0 ? BQ_O : (proj == 1 ? BK_O : BV_O));

  #pragma unroll
  for (int it = 0; it < 8; ++it) {
    int row = it * 16 + (tid >> 4);
    int col = (tid & 15) * 8;
    *(bf16x8*)&X[row][col] =
        *(const bf16x8*)(featb + ((size_t)(bat * CD + row)) * NPOS + n0 + col);
  }
  __syncthreads();

  int wr = w >> 1, wc = w & 1;
  f32x4 acc[4][4];
  #pragma unroll
  for (int m = 0; m < 4; ++m)
    #pragma unroll
    for (int n = 0; n < 4; ++n) acc[m][n] = (f32x4){0.f, 0.f, 0.f, 0.f};

  #pragma unroll
  for (int ks = 0; ks < 4; ++ks) {
    int c0 = ks * 32 + 8 * hi;
    bf16x8 a[4], bb[4];
    #pragma unroll
    for (int m = 0; m < 4; ++m) {
      int o = wr * 64 + m * 16 + lo;
      a[m] = *(const bf16x8*)(W + o * CD + c0);
    }
    #pragma unroll
    for (int n = 0; n < 4; ++n) {
      int nn = wc * 64 + n * 16 + lo;
      bf16x8 t;
      #pragma unroll
      for (int e = 0; e < 8; ++e) t[e] = (short)X[c0 + e][nn];
      bb[n] = t;
    }
    #pragma unroll
    for (int m = 0; m < 4; ++m)
      #pragma unroll
      for (int n = 0; n < 4; ++n)
        acc[m][n] = __builtin_amdgcn_mfma_f32_16x16x32_bf16(a[m], bb[n], acc[m][n], 0, 0, 0);
  }

  #pragma unroll
  for (int m = 0; m < 4; ++m) {
    int o0 = wr * 64 + m * 16 + hi * 4;
    float bsv[4];
    #pragma unroll
    for (int r = 0; r < 4; ++r) bsv[r] = b2f(bias[o0 + r]);
    #pragma unroll
    for (int n = 0; n < 4; ++n) {
      int nn = n0 + wc * 64 + n * 16 + lo;
      if (proj < 2) {
        unsigned short* O = proj == 0 ? QT : KT;
        us4 pk;
        #pragma unroll
        for (int r = 0; r < 4; ++r) pk[r] = f2b(acc[m][n][r] + bsv[r]);
        *(us4*)(O + ((size_t)(bat * NPOS + nn)) * CD + o0) = pk;
      } else {
        #pragma unroll
        for (int r = 0; r < 4; ++r)
          Vm[((size_t)(bat * CD + o0 + r)) * NPOS + nn] = f2b(acc[m][n][r] + bsv[r]);
      }
    }
  }
}

// ---------- Kernel 3: fused attention (transposed QK^T, vector att/H loads) ----------
// grid (128 o-tiles of 32 rows, 2 batch), block 512 = 8 waves, each a 64-wide i slice.
// S^T = mfma(A=K, B=Q): lane holds i = rf*16 + 4*hi + rr (contiguous rr), o = cf*16 + lo.
__global__ __launch_bounds__(512, 1) void attn_kernel(
    const int* __restrict__ flag,
    const unsigned short* __restrict__ QT, const unsigned short* __restrict__ KT,
    const unsigned short* __restrict__ Vm, const void* __restrict__ att,
    const void* __restrict__ Hm, unsigned short* __restrict__ MT) {
  __shared__ __attribute__((aligned(16))) unsigned short Pl[8][32][72];
  __shared__ float mred[8][32], lred[8][32];
  __shared__ float Olds[32][132];

  bool f32 = (*flag != 0);
  const float* attf = (const float*)att;
  const float* hmf = (const float*)Hm;
  const unsigned short* attu = (const unsigned short*)att;
  const unsigned short* hmu = (const unsigned short*)Hm;

  int tid = threadIdx.x;
  int w = tid >> 6, lane = tid & 63;
  int hi = lane >> 4, lo = lane & 15;
  int ob = blockIdx.x * 32;
  int bat = blockIdx.y;
  const float SCL = 0.088388347648318447f;  // 1/sqrt(128)

  // Q fragments (B operand) for this block's 32 o-rows — fixed across iters
  bf16x8 qf[2][4];
  #pragma unroll
  for (int cf = 0; cf < 2; ++cf)
    #pragma unroll
    for (int ks = 0; ks < 4; ++ks)
      qf[cf][ks] = *(const bf16x8*)(QT + ((size_t)(bat * NPOS + ob + cf * 16 + lo)) * CD +
                                    ks * 32 + 8 * hi);

  f32x4 oacc[2][8];
  #pragma unroll
  for (int rp = 0; rp < 2; ++rp)
    #pragma unroll
    for (int c8 = 0; c8 < 8; ++c8) oacc[rp][c8] = (f32x4){0.f, 0.f, 0.f, 0.f};
  float mrun[2], lrun[2];
  #pragma unroll
  for (int cf = 0; cf < 2; ++cf) { mrun[cf] = -1e30f; lrun[cf] = 0.f; }

  for (int it = 0; it < 8; ++it) {
    int i0w = it * 512 + w * 64;

    // --- vector att/H loads: b64 (4 bf16, contiguous i) per (cf, rf) ---
    us4 av[2][4], hv[2][4];
    #pragma unroll
    for (int cf = 0; cf < 2; ++cf)
      #pragma unroll
      for (int rf = 0; rf < 4; ++rf) {
        size_t idx = ((size_t)(bat * NPOS + ob + cf * 16 + lo)) * NPOS +
                     i0w + rf * 16 + 4 * hi;
        if (f32) {
          // fall back: scalar gathers (never taken when inputs are bf16)
          us4 a, h;
          #pragma unroll
          for (int rr = 0; rr < 4; ++rr) {
            a[rr] = f2b(attf[idx + rr]);
            h[rr] = f2b(hmf[idx + rr]);
          }
          av[cf][rf] = a; hv[cf][rf] = h;
        } else {
          av[cf][rf] = *(const us4*)(attu + idx);
          hv[cf][rf] = *(const us4*)(hmu + idx);
        }
      }

    // --- S^T = K Q^T (A=K frags, B=Q frags) ---
    f32x4 s2[4][2];
    #pragma unroll
    for (int rf = 0; rf < 4; ++rf)
      #pragma unroll
      for (int cf = 0; cf < 2; ++cf) s2[rf][cf] = (f32x4){0.f, 0.f, 0.f, 0.f};
    #pragma unroll
    for (int ks = 0; ks < 4; ++ks) {
      bf16x8 kf[4];
      #pragma unroll
      for (int rf = 0; rf < 4; ++rf)
        kf[rf] = *(const bf16x8*)(KT + ((size_t)(bat * NPOS + i0w + rf * 16 + lo)) * CD +
                                  ks * 32 + 8 * hi);
      #pragma unroll
      for (int rf = 0; rf < 4; ++rf) {
        s2[rf][0] = __builtin_amdgcn_mfma_f32_16x16x32_bf16(kf[rf], qf[0][ks], s2[rf][0], 0, 0, 0);
        s2[rf][1] = __builtin_amdgcn_mfma_f32_16x16x32_bf16(kf[rf], qf[1][ks], s2[rf][1], 0, 0, 0);
      }
    }

    // --- logits + per-o-row max (16 i-values per lane per cf) ---
    float lg[2][4][4], mx[2];
    #pragma unroll
    for (int cf = 0; cf < 2; ++cf) {
      float m = -1e30f;
      #pragma unroll
      for (int rf = 0; rf < 4; ++rf)
        #pragma unroll
        for (int rr = 0; rr < 4; ++rr) {
          float a = b2f(av[cf][rf][rr]);
          bool msk = b2f(hv[cf][rf][rr]) < 0.5f;
          float v = msk ? -1e9f : a * SCL * s2[rf][cf][rr];
          lg[cf][rf][rr] = v;
          m = fmaxf(m, v);
        }
      m = fmaxf(m, __shfl_xor(m, 16, 64));
      m = fmaxf(m, __shfl_xor(m, 32, 64));
      mx[cf] = m;
    }

    // --- online softmax update ---
    float psc[2];
    #pragma unroll
    for (int cf = 0; cf < 2; ++cf) {
      float mo = mrun[cf];
      float mn = fmaxf(mo, mx[cf]);
      psc[cf] = __expf(mo - mn);
      mrun[cf] = mn;
    }

    // P = exp(lg - m): write b64 to LDS, accumulate row sums
    #pragma unroll
    for (int cf = 0; cf < 2; ++cf) {
      float t = 0.f;
      #pragma unroll
      for (int rf = 0; rf < 4; ++rf) {
        us4 pk;
        #pragma unroll
        for (int rr = 0; rr < 4; ++rr) {
          float p = __expf(lg[cf][rf][rr] - mrun[cf]);
          t += p;
          pk[rr] = f2b(p);
        }
        *(us4*)&Pl[w][cf * 16 + lo][rf * 16 + 4 * hi] = pk;
      }
      t += __shfl_xor(t, 16, 64);
      t += __shfl_xor(t, 32, 64);
      lrun[cf] = lrun[cf] * psc[cf] + t;
    }

    // rescale O accumulator: broadcast psc to D-layout lanes (o = rp*16 + 4*hi + rr)
    #pragma unroll
    for (int rp = 0; rp < 2; ++rp) {
      #pragma unroll
      for (int rr = 0; rr < 4; ++rr) {
        float sc = __shfl(psc[rp], 4 * hi + rr, 64);
        #pragma unroll
        for (int c8 = 0; c8 < 8; ++c8) oacc[rp][c8][rr] *= sc;
      }
    }

    // --- PV accumulate: A = P (from LDS), B = V ---
    bf16x8 pa[2][2];
    #pragma unroll
    for (int rp = 0; rp < 2; ++rp)
      #pragma unroll
      for (int ks = 0; ks < 2; ++ks)
        pa[rp][ks] = *(const bf16x8*)&Pl[w][rp * 16 + lo][ks * 32 + 8 * hi];
    #pragma unroll
    for (int ks = 0; ks < 2; ++ks)
      #pragma unroll
      for (int c8 = 0; c8 < 8; ++c8) {
        bf16x8 bb = *(const bf16x8*)(Vm + ((size_t)(bat * CD + c8 * 16 + lo)) * NPOS +
                                     i0w + ks * 32 + 8 * hi);
        oacc[0][c8] = __builtin_amdgcn_mfma_f32_16x16x32_bf16(pa[0][ks], bb, oacc[0][c8], 0, 0, 0);
        oacc[1][c8] = __builtin_amdgcn_mfma_f32_16x16x32_bf16(pa[1][ks], bb, oacc[1][c8], 0, 0, 0);
      }
  }

  // ------- cross-wave merge -------
  #pragma unroll
  for (int cf = 0; cf < 2; ++cf)
    if (hi == 0) { mred[w][cf * 16 + lo] = mrun[cf]; lred[w][cf * 16 + lo] = lrun[cf]; }
  __syncthreads();

  #pragma unroll
  for (int rp = 0; rp < 2; ++rp) {
    #pragma unroll
    for (int rr = 0; rr < 4; ++rr) {
      int o = rp * 16 + 4 * hi + rr;
      float ms = mred[0][o];
      #pragma unroll
      for (int v = 1; v < 8; ++v) ms = fmaxf(ms, mred[v][o]);
      float mw = __shfl(mrun[rp], 4 * hi + rr, 64);
      float fs = __expf(mw - ms);
      #pragma unroll
      for (int c8 = 0; c8 < 8; ++c8) oacc[rp][c8][rr] *= fs;
    }
  }

  for (int v = 0; v < 8; ++v) {
    if (w == v) {
      #pragma unroll
      for (int rp = 0; rp < 2; ++rp)
        #pragma unroll
        for (int c8 = 0; c8 < 8; ++c8)
          #pragma unroll
          for (int rr = 0; rr < 4; ++rr) {
            int row = rp * 16 + 4 * hi + rr, col = c8 * 16 + lo;
            if (v == 0) Olds[row][col] = oacc[rp][c8][rr];
            else Olds[row][col] += oacc[rp][c8][rr];
          }
    }
    __syncthreads();
  }

  // normalize + write message^T [b][n][c]
  {
    int row = tid >> 4, c0 = (tid & 15) * 8;
    float ms = mred[0][row];
    #pragma unroll
    for (int v = 1; v < 8; ++v) ms = fmaxf(ms, mred[v][row]);
    float L = 0.f;
    #pragma unroll
    for (int v = 0; v < 8; ++v) L += lred[v][row] * __expf(mred[v][row] - ms);
    float inv = 1.f / fmaxf(L, 1e-30f);
    bf16x8 p1;
    #pragma unroll
    for (int j = 0; j < 8; ++j) p1[j] = (short)f2b(Olds[row][c0 + j] * inv);
    *(bf16x8*)(MT + ((size_t)(bat * NPOS + ob + row)) * CD + c0) = p1;
  }
}

// ---------- Kernel 4: fused MLP + residual ----------
__global__ __launch_bounds__(256) void mlp_kernel(
    const int* __restrict__ flag,
    const unsigned short* __restrict__ MT, const unsigned short* __restrict__ featb,
    const unsigned short* __restrict__ wb, void* __restrict__ out) {
  __shared__ __attribute__((aligned(16))) unsigned short M1T[128][72];
  __shared__ __attribute__((aligned(16))) unsigned short M2T[128][72];
  __shared__ __attribute__((aligned(16))) unsigned short OT[128][136];
  __shared__ float A1[64], B1[64], A2[64], B2[64], BI3[128];

  bool f32 = (*flag != 0);
  int tid = threadIdx.x;
  int w = tid >> 6, lane = tid & 63;
  int hi = lane >> 4, lo = lane & 15;
  int n0 = blockIdx.x * 128;
  int bat = blockIdx.y;

  float rs = rsqrtf(1.0f + 1e-5f);
  if (tid < 64) {
    float s1 = b2f(wb[G1_O + tid]) * rs;
    A1[tid] = s1; B1[tid] = s1 * b2f(wb[B1_O + tid]) + b2f(wb[BE1_O + tid]);
    float s2 = b2f(wb[G2_O + tid]) * rs;
    A2[tid] = s2; B2[tid] = s2 * b2f(wb[B2_O + tid]) + b2f(wb[BE2_O + tid]);
  }
  if (tid < 128) BI3[tid] = b2f(wb[B3_O + tid]);
  __syncthreads();

  f32x4 acc1[4][2];
  #pragma unroll
  for (int m = 0; m < 4; ++m)
    #pragma unroll
    for (int n = 0; n < 2; ++n) acc1[m][n] = (f32x4){0.f, 0.f, 0.f, 0.f};
  #pragma unroll
  for (int ks = 0; ks < 4; ++ks) {
    bf16x8 bw[2];
    #pragma unroll
    for (int n = 0; n < 2; ++n)
      bw[n] = *(const bf16x8*)(MT + ((size_t)(bat * NPOS + n0 + w * 32 + n * 16 + lo)) * CD +
                               ks * 32 + 8 * hi);
    #pragma unroll
    for (int m = 0; m < 4; ++m) {
      bf16x8 aw = *(const bf16x8*)(wb + W1_O + (m * 16 + lo) * CD + ks * 32 + 8 * hi);
      #pragma unroll
      for (int n = 0; n < 2; ++n)
        acc1[m][n] = __builtin_amdgcn_mfma_f32_16x16x32_bf16(aw, bw[n], acc1[m][n], 0, 0, 0);
    }
  }
  #pragma unroll
  for (int m = 0; m < 4; ++m)
    #pragma unroll
    for (int n = 0; n < 2; ++n) {
      int h0 = m * 16 + hi * 4;
      int nn = w * 32 + n * 16 + lo;
      us4 pk;
      #pragma unroll
      for (int r = 0; r < 4; ++r) {
        float v = A1[h0 + r] * acc1[m][n][r] + B1[h0 + r];
        pk[r] = f2b(fmaxf(v, 0.f));
      }
      *(us4*)&M1T[nn][h0] = pk;
    }

  f32x4 acc2[4][2];
  #pragma unroll
  for (int m = 0; m < 4; ++m)
    #pragma unroll
    for (int n = 0; n < 2; ++n) acc2[m][n] = (f32x4){0.f, 0.f, 0.f, 0.f};
  #pragma unroll
  for (int ks = 0; ks < 2; ++ks) {
    bf16x8 bw[2];
    #pragma unroll
    for (int n = 0; n < 2; ++n)
      bw[n] = *(const bf16x8*)&M1T[w * 32 + n * 16 + lo][ks * 32 + 8 * hi];
    #pragma unroll
    for (int m = 0; m < 4; ++m) {
      bf16x8 aw = *(const bf16x8*)(wb + W2_O + (m * 16 + lo) * 64 + ks * 32 + 8 * hi);
      #pragma unroll
      for (int n = 0; n < 2; ++n)
        acc2[m][n] = __builtin_amdgcn_mfma_f32_16x16x32_bf16(aw, bw[n], acc2[m][n], 0, 0, 0);
    }
  }
  #pragma unroll
  for (int m = 0; m < 4; ++m)
    #pragma unroll
    for (int n = 0; n < 2; ++n) {
      int h0 = m * 16 + hi * 4;
      int nn = w * 32 + n * 16 + lo;
      us4 pk;
      #pragma unroll
      for (int r = 0; r < 4; ++r) {
        float v = A2[h0 + r] * acc2[m][n][r] + B2[h0 + r];
        pk[r] = f2b(fmaxf(v, 0.f));
      }
      *(us4*)&M2T[nn][h0] = pk;
    }

  f32x4 acc3[8][2];
  #pragma unroll
  for (int m = 0; m < 8; ++m)
    #pragma unroll
    for (int n = 0; n < 2; ++n) acc3[m][n] = (f32x4){0.f, 0.f, 0.f, 0.f};
  #pragma unroll
  for (int ks = 0; ks < 2; ++ks) {
    bf16x8 bw[2];
    #pragma unroll
    for (int n = 0; n < 2; ++n)
      bw[n] = *(const bf16x8*)&M2T[w * 32 + n * 16 + lo][ks * 32 + 8 * hi];
    #pragma unroll
    for (int m = 0; m < 8; ++m) {
      bf16x8 aw = *(const bf16x8*)(wb + W3_O + (m * 16 + lo) * 64 + ks * 32 + 8 * hi);
      #pragma unroll
      for (int n = 0; n < 2; ++n)
        acc3[m][n] = __builtin_amdgcn_mfma_f32_16x16x32_bf16(aw, bw[n], acc3[m][n], 0, 0, 0);
    }
  }
  #pragma unroll
  for (int m = 0; m < 8; ++m)
    #pragma unroll
    for (int n = 0; n < 2; ++n)
      #pragma unroll
      for (int r = 0; r < 4; ++r) {
        int c = m * 16 + hi * 4 + r;
        int nn = w * 32 + n * 16 + lo;
        OT[c][nn] = f2b(acc3[m][n][r] + BI3[c]);
      }
  __syncthreads();

  {
    int c = tid >> 1, nb = (tid & 1) * 64;
    #pragma unroll
    for (int j = 0; j < 8; ++j) {
      bf16x8 mv = *(bf16x8*)&OT[c][nb + 8 * j];
      const unsigned short* fp = featb + ((size_t)(bat * CD + c)) * NPOS + n0 + nb + 8 * j;
      bf16x8 fv = *(const bf16x8*)fp;
      float vals[8];
      #pragma unroll
      for (int e = 0; e < 8; ++e)
        vals[e] = b2f((unsigned short)mv[e]) + b2f((unsigned short)fv[e]);
      size_t oidx = ((size_t)(bat * CD + c)) * NPOS + n0 + nb + 8 * j;
      if (f32) {
        float* of = (float*)out;
        f32x4 v0 = {vals[0], vals[1], vals[2], vals[3]};
        f32x4 v1 = {vals[4], vals[5], vals[6], vals[7]};
        *(f32x4*)(of + oidx) = v0;
        *(f32x4*)(of + oidx + 4) = v1;
      } else {
        unsigned short* ou = (unsigned short*)out;
        bf16x8 ov;
        #pragma unroll
        for (int e = 0; e < 8; ++e) ov[e] = (short)f2b(vals[e]);
        *(bf16x8*)(ou + oidx) = ov;
      }
    }
  }
}

extern "C" void kernel_launch(void* const* d_in, const int* in_sizes, int n_in,
                              void* d_out, int out_size, void* d_ws, size_t ws_size,
                              hipStream_t stream) {
  const void* feat = d_in[0];
  const void* att  = d_in[1];
  const void* Wq = d_in[2];  const void* bq = d_in[3];
  const void* Wk = d_in[4];  const void* bk = d_in[5];
  const void* Wv = d_in[6];  const void* bv = d_in[7];
  const void* W1 = d_in[8];  const void* b1 = d_in[9];
  const void* g1 = d_in[10]; const void* be1 = d_in[11];
  const void* W2 = d_in[12]; const void* b2 = d_in[13];
  const void* g2 = d_in[14]; const void* be2 = d_in[15];
  const void* W3 = d_in[16]; const void* b3 = d_in[17];
  const void* Hm = d_in[18];

  int* flag = (int*)d_ws;
  unsigned short* base = (unsigned short*)((char*)d_ws + 256);
  unsigned short* featb = base;                        // 1,048,576 elems
  unsigned short* wb = featb + (size_t)2 * CD * NPOS;  // 70,656
  unsigned short* QT = wb + WB_ELEMS;                  // [2][4096][128]
  unsigned short* KT = QT + (size_t)2 * NPOS * CD;     // [2][4096][128]
  unsigned short* Vm = KT + (size_t)2 * NPOS * CD;     // [2][128][4096]
  unsigned short* MT = Vm + (size_t)2 * NPOS * CD;     // [2][4096][128]

  hipLaunchKernelGGL(probe_kernel, dim3(1), dim3(64), 0, stream,
                     (const unsigned short*)att, flag);
  hipLaunchKernelGGL(prep_kernel, dim3(256), dim3(256), 0, stream,
                     flag, feat, Wq, bq, Wk, bk, Wv, bv, W1, b1, g1, be1,
                     W2, b2, g2, be2, W3, b3, featb, wb);
  hipLaunchKernelGGL(qkv_kernel, dim3(32, 3, 2), dim3(256), 0, stream,
                     featb, wb, QT, KT, Vm);
  hipLaunchKernelGGL(attn_kernel, dim3(128, 2), dim3(512), 0, stream,
                     flag, QT, KT, Vm, att, Hm, MT);
  hipLaunchKernelGGL(mlp_kernel, dim3(32, 2), dim3(256), 0, stream,
                     flag, MT, featb, wb, d_out);
}